// Round 15
// baseline (419.954 us; speedup 1.0000x reference)
//
#include <hip/hip_runtime.h>
#include <hip/hip_bf16.h>

#define BN_EPS 1e-5f

typedef __attribute__((ext_vector_type(8))) short short8v;
typedef __attribute__((ext_vector_type(4))) float f32x4;
typedef _Float16 f16x2 __attribute__((ext_vector_type(2)));
typedef __hip_bfloat16 bf16;
typedef unsigned short ushort_t;
typedef unsigned int uint_t;

// ---------------------------------------------------------------- CSR build
__global__ void count_kernel(const int* __restrict__ dst, int* __restrict__ deg,
                             int E, int N) {
    int i = blockIdx.x * blockDim.x + threadIdx.x;
    if (i >= E) return;
    int d = dst[i];
    d = min(max(d, 0), N - 1);
    atomicAdd(&deg[d], 1);
}

// pass 1 — per-block sums (256 elems/block)
__global__ __launch_bounds__(256) void scan1_kernel(const int* __restrict__ deg,
                                                    int* __restrict__ bsum, int N) {
    int t = threadIdx.x, b = blockIdx.x;
    int i = b * 256 + t;
    int v = (i < N) ? deg[i] : 0;
#pragma unroll
    for (int d = 32; d; d >>= 1) v += __shfl_xor(v, d, 64);
    __shared__ int ws[4];
    if ((t & 63) == 0) ws[t >> 6] = v;
    __syncthreads();
    if (t == 0) bsum[b] = ws[0] + ws[1] + ws[2] + ws[3];
}

// pass 2 — per-block scan; block base computed internally from bsum[0..b)
__global__ __launch_bounds__(256) void scan3_kernel(const int* __restrict__ deg,
                                                    const int* __restrict__ bsum,
                                                    int* __restrict__ off,
                                                    int* __restrict__ cur,
                                                    int N, int nb) {
    int t = threadIdx.x, b = blockIdx.x;
    int lane = t & 63, w = t >> 6;

    int partial = 0;
    for (int j = t; j < b; j += 256) partial += bsum[j];
#pragma unroll
    for (int d = 32; d; d >>= 1) partial += __shfl_xor(partial, d, 64);
    __shared__ int bsm[4];
    if (lane == 0) bsm[w] = partial;
    __syncthreads();
    int base = bsm[0] + bsm[1] + bsm[2] + bsm[3];

    int i = b * 256 + t;
    int v = (i < N) ? deg[i] : 0;
    int inc = v;
#pragma unroll
    for (int d = 1; d < 64; d <<= 1) {
        int u = __shfl_up(inc, d, 64);
        if (lane >= d) inc += u;
    }
    __shared__ int ws[4];
    if (lane == 63) ws[w] = inc;
    __syncthreads();
    for (int j = 0; j < w; ++j) base += ws[j];
    int excl = base + inc - v;
    if (i < N) { off[i] = excl; cur[i] = excl; }
    if (i == N - 1) off[N] = excl + v;
}

// fill: CSR edge placement; emits permuted src ids AND permuted edge_attr
// packed as 8 x (2 x f16) per edge
__global__ void fill_kernel(const int* __restrict__ src, const int* __restrict__ dst,
                            const float* __restrict__ ea, int* __restrict__ cur,
                            int* __restrict__ srcs, uint_t* __restrict__ each,
                            int E, int N) {
    int i = blockIdx.x * blockDim.x + threadIdx.x;
    if (i >= E) return;
    int d = dst[i];
    d = min(max(d, 0), N - 1);
    int p = atomicAdd(&cur[d], 1);
    srcs[p] = min(max(src[i], 0), N - 1);
    uint_t pk[8];
#pragma unroll
    for (int q = 0; q < 4; ++q) {
        float4 a = *(const float4*)&ea[(size_t)i * 16 + q * 4];
        f16x2 h0 = {(_Float16)a.x, (_Float16)a.y};
        f16x2 h1 = {(_Float16)a.z, (_Float16)a.w};
        pk[q * 2 + 0] = __builtin_bit_cast(uint_t, h0);
        pk[q * 2 + 1] = __builtin_bit_cast(uint_t, h1);
    }
    *(uint4*)&each[(size_t)p * 8 + 0] = *(uint4*)&pk[0];
    *(uint4*)&each[(size_t)p * 8 + 4] = *(uint4*)&pk[4];
}

// ------------------------------------------- mega convert + zero kernel
// MLP weights packed into MFMA B-fragment order:
//   wt[base + ((nt*ktn + kt)*64 + lane)*8 + j] = w[k][col]
//   col = nt*16 + (lane&15),  k = kt*32 + (lane>>4)*8 + j
// -> a wave's fragment load is lane-contiguous (1 KB coalesced).
__global__ void megaconv_kernel(
    const float* __restrict__ x, bf16* __restrict__ xb, int nx4,
    const float* __restrict__ w1a, const float* __restrict__ w1b,
    const float* __restrict__ w2a, const float* __restrict__ w2b,
    const float* __restrict__ w3a, const float* __restrict__ w3b,
    bf16* __restrict__ wt,
    const float* __restrict__ we1, const float* __restrict__ we2,
    const float* __restrict__ we3, uint_t* __restrict__ wef,
    int* __restrict__ deg, int N, float* __restrict__ pooled) {
    int t = blockIdx.x * blockDim.x + threadIdx.x;
    if (t < nx4) {
        int i = t * 4;
        float4 v = *(const float4*)&x[i];
        xb[i + 0] = __float2bfloat16(v.x);
        xb[i + 1] = __float2bfloat16(v.y);
        xb[i + 2] = __float2bfloat16(v.z);
        xb[i + 3] = __float2bfloat16(v.w);
        return;
    }
    t -= nx4;
    if (t < 143360) {
        const float* w; int K, Nc, base, r;
        if (t < 16384)       { w = w1a; K = 64;  Nc = 256; base = 0;      r = t; }
        else if (t < 81920)  { w = w1b; K = 256; Nc = 256; base = 16384;  r = t - 16384; }
        else if (t < 114688) { w = w2a; K = 256; Nc = 128; base = 81920;  r = t - 81920; }
        else if (t < 131072) { w = w2b; K = 128; Nc = 128; base = 114688; r = t - 114688; }
        else if (t < 139264) { w = w3a; K = 128; Nc = 64;  base = 131072; r = t - 131072; }
        else                 { w = w3b; K = 64;  Nc = 64;  base = 139264; r = t - 139264; }
        int ktn = K / 32;
        int j = r & 7;
        int lane = (r >> 3) & 63;
        int rem = r >> 9;
        int kt = rem % ktn;
        int nt = rem / ktn;
        int col = nt * 16 + (lane & 15);
        int k = kt * 32 + ((lane >> 4) << 3) + j;
        wt[base + r] = __float2bfloat16(w[(size_t)k * Nc + col]);
        return;
    }
    t -= 143360;
    if (t < 3584) {
        const float* w; int D, base, r;
        if (t < 512)        { w = we1; D = 64;  base = 0;    r = t; }
        else if (t < 2560)  { w = we2; D = 256; base = 512;  r = t - 512; }
        else                { w = we3; D = 128; base = 2560; r = t - 2560; }
        int p = r / D, col = r % D;
        f16x2 h = {(_Float16)w[(size_t)(2 * p) * D + col],
                   (_Float16)w[(size_t)(2 * p + 1) * D + col]};
        wef[base + r] = __builtin_bit_cast(uint_t, h);
        return;
    }
    t -= 3584;
    {
        int nd4 = (N + 3) / 4;
        if (t < nd4) {
            int i = t * 4;
#pragma unroll
            for (int j = 0; j < 4; ++j)
                if (i + j < N) deg[i + j] = 0;
            return;
        }
        t -= nd4;
        if (t < 2048) {
            *(float4*)&pooled[t * 4] = make_float4(0.f, 0.f, 0.f, 0.f);
        }
    }
}

// ------------------------------------------------- fused message + aggregate
// t[n] = x[n] + sum_p relu(x[srcs[p]] + e[p] @ we + be)
// One wave per node; lane covers cols [lane*C, lane*C+C).
// __launch_bounds__(256,4): 128-VGPR budget so wreg[8][C] stays RESIDENT
// (at the default budget the compiler reloads weights from L1 every use —
// VGPR_Count=32 in r10/r14 proves it). j-outer compute keeps live m[] small.
template <int C>
__global__ __launch_bounds__(256, 4) void msg_fused(
    const uint_t* __restrict__ each, const int* __restrict__ srcs,
    const int* __restrict__ off, const bf16* __restrict__ x,
    const uint_t* __restrict__ wef, const float* __restrict__ be,
    bf16* __restrict__ t, int N) {
    constexpr int D = C * 64;
    const int lane = threadIdx.x & 63;
    const int n = blockIdx.x * 4 + (threadIdx.x >> 6);
    if (n >= N) return;
    const int col0 = lane * C;

    uint_t wreg[8][C];
#pragma unroll
    for (int p = 0; p < 8; ++p)
#pragma unroll
        for (int c = 0; c < C; ++c) wreg[p][c] = wef[p * D + col0 + c];
    float breg[C];
#pragma unroll
    for (int c = 0; c < C; ++c) breg[c] = be[col0 + c];

    float acc[C];
#pragma unroll
    for (int c = 0; c < C; ++c) acc[c] = 0.f;

    const ushort_t* xp = (const ushort_t*)x;

    const int i0 = __builtin_amdgcn_readfirstlane(off[n]);
    const int i1 = __builtin_amdgcn_readfirstlane(off[n + 1]);

#define BF2F(u) (__builtin_bit_cast(float, (unsigned)(u) << 16))
#define H2(u) (__builtin_bit_cast(f16x2, u))

    int i = i0;
    int sN[4] = {0, 0, 0, 0};
    if (i + 4 <= i1) {
#pragma unroll
        for (int j = 0; j < 4; ++j)
            sN[j] = __builtin_amdgcn_readfirstlane(srcs[i + j]);
    }
    for (; i + 4 <= i1; i += 4) {
        int s[4];
#pragma unroll
        for (int j = 0; j < 4; ++j) s[j] = sN[j];
        // all 4 x gathers in flight first (addresses ready from prev iter)
        ushort_t xv[4][C];
#pragma unroll
        for (int j = 0; j < 4; ++j) {
            if constexpr (C == 4) {
                *(ushort4*)xv[j] = *(const ushort4*)&xp[(size_t)s[j] * D + col0];
            } else if constexpr (C == 2) {
                *(ushort2*)xv[j] = *(const ushort2*)&xp[(size_t)s[j] * D + col0];
            } else {
                xv[j][0] = xp[(size_t)s[j] * D + col0];
            }
        }
        if (i + 8 <= i1) {
#pragma unroll
            for (int j = 0; j < 4; ++j)
                sN[j] = __builtin_amdgcn_readfirstlane(srcs[i + 4 + j]);
        }
        // wave-uniform packed edge-attr rows (scalar loads)
        uint_t e[4][8];
#pragma unroll
        for (int j = 0; j < 4; ++j)
#pragma unroll
            for (int p = 0; p < 8; ++p) e[j][p] = each[(size_t)(i + j) * 8 + p];

        // j-outer: one edge's full MLP at a time (live m[] = C regs)
#pragma unroll
        for (int j = 0; j < 4; ++j) {
            float m[C];
#pragma unroll
            for (int c = 0; c < C; ++c)
                m[c] = __builtin_amdgcn_fdot2(H2(e[j][0]), H2(wreg[0][c]), breg[c], false);
#pragma unroll
            for (int p = 1; p < 8; ++p)
#pragma unroll
                for (int c = 0; c < C; ++c)
                    m[c] = __builtin_amdgcn_fdot2(H2(e[j][p]), H2(wreg[p][c]), m[c], false);
#pragma unroll
            for (int c = 0; c < C; ++c)
                acc[c] += fmaxf(m[c] + BF2F(xv[j][c]), 0.f);
        }
    }
    // tail (< 4 edges)
    for (; i < i1; ++i) {
        const int s0 = __builtin_amdgcn_readfirstlane(srcs[i]);
        ushort_t xv0[C];
        if constexpr (C == 4) {
            *(ushort4*)xv0 = *(const ushort4*)&xp[(size_t)s0 * D + col0];
        } else if constexpr (C == 2) {
            *(ushort2*)xv0 = *(const ushort2*)&xp[(size_t)s0 * D + col0];
        } else {
            xv0[0] = xp[(size_t)s0 * D + col0];
        }
        uint_t e0[8];
#pragma unroll
        for (int p = 0; p < 8; ++p) e0[p] = each[(size_t)i * 8 + p];
        float m0[C];
#pragma unroll
        for (int c = 0; c < C; ++c)
            m0[c] = __builtin_amdgcn_fdot2(H2(e0[0]), H2(wreg[0][c]), breg[c], false);
#pragma unroll
        for (int p = 1; p < 8; ++p)
#pragma unroll
            for (int c = 0; c < C; ++c)
                m0[c] = __builtin_amdgcn_fdot2(H2(e0[p]), H2(wreg[p][c]), m0[c], false);
#pragma unroll
        for (int c = 0; c < C; ++c) acc[c] += fmaxf(m0[c] + BF2F(xv0[c]), 0.f);
    }

#pragma unroll
    for (int c = 0; c < C; ++c) {
        float xo = BF2F(xp[(size_t)n * D + col0 + c]);
        t[(size_t)n * D + col0 + c] = __float2bfloat16(xo + acc[c]);
    }
#undef BF2F
#undef H2
}

// --------------------------------------------------------- bf16 MFMA GEMM
// 64 rows/wave (4 A-frags), 64 cols/block via blockIdx.y.
// W pre-packed in fragment order -> lane-contiguous 1KB coalesced B loads.
// grid = (M/256, NC/64), 256 threads (4 waves x 64 rows).
// mode 1: relu -> C   mode 2: bn(relu) -> C   mode 3: bn(relu) + atomic pool
template <int NC>
__global__ __launch_bounds__(256) void gemm64(
    const bf16* __restrict__ A, const bf16* __restrict__ Wp_,
    const float* __restrict__ bias, const float* __restrict__ bng,
    const float* __restrict__ bnb, const float* __restrict__ bnm,
    const float* __restrict__ bnv, bf16* __restrict__ C,
    const int* __restrict__ batch, float* __restrict__ pooled,
    int M, int K, int mode) {
    const int lane = threadIdx.x & 63;
    const int w = threadIdx.x >> 6;
    const int r16 = lane & 15;
    const int kg = lane >> 4;
    const int mbase = blockIdx.x * 256 + w * 64;
    const int nbase = blockIdx.y * 64;
    const int ktn = K >> 5;

    f32x4 acc[4][4];
#pragma unroll
    for (int f = 0; f < 4; ++f)
#pragma unroll
        for (int nt = 0; nt < 4; ++nt) acc[f][nt] = (f32x4){0.f, 0.f, 0.f, 0.f};

    const short* Ap = (const short*)A;
    const short* Wp = (const short*)Wp_;

    for (int kt = 0; kt < ktn; ++kt) {
        short8v b[4];
#pragma unroll
        for (int nt = 0; nt < 4; ++nt)
            b[nt] = *(const short8v*)&Wp[(((size_t)(blockIdx.y * 4 + nt) * ktn + kt) * 64 + lane) * 8];
        short8v a[4];
#pragma unroll
        for (int f = 0; f < 4; ++f)
            a[f] = *(const short8v*)&Ap[(size_t)(mbase + f * 16 + r16) * K + kt * 32 + kg * 8];
#pragma unroll
        for (int f = 0; f < 4; ++f)
#pragma unroll
            for (int nt = 0; nt < 4; ++nt)
                acc[f][nt] = __builtin_amdgcn_mfma_f32_16x16x32_bf16(a[f], b[nt], acc[f][nt], 0, 0, 0);
    }

    float bs[4], sc[4], sh[4];
#pragma unroll
    for (int nt = 0; nt < 4; ++nt) {
        int col = nbase + nt * 16 + r16;
        bs[nt] = bias[col];
        sc[nt] = 1.f; sh[nt] = 0.f;
        if (mode >= 2) {
            sc[nt] = rsqrtf(bnv[col] + BN_EPS) * bng[col];
            sh[nt] = bnb[col] - bnm[col] * sc[nt];
        }
    }

#pragma unroll
    for (int f = 0; f < 4; ++f) {
#pragma unroll
        for (int rg = 0; rg < 4; ++rg) {
            int row = mbase + f * 16 + kg * 4 + rg;
            if (row >= M) continue;
            int g = 0;
            if (mode == 3) g = min(max(batch[row], 0), 127);
#pragma unroll
            for (int nt = 0; nt < 4; ++nt) {
                int col = nbase + nt * 16 + r16;
                float z = acc[f][nt][rg] + bs[nt];
                z = fmaxf(z, 0.f);
                if (mode >= 2) z = z * sc[nt] + sh[nt];
                if (mode == 3)
                    atomicAdd(&pooled[g * NC + col], z);
                else
                    C[(size_t)row * NC + col] = __float2bfloat16(z);
            }
        }
    }
}

// -------------------------------------------------------------------- head
__global__ __launch_bounds__(128) void head_kernel(
    const float* __restrict__ pooled, const float* __restrict__ w1,
    const float* __restrict__ b1, const float* __restrict__ w2,
    const float* __restrict__ b2, float* __restrict__ out) {
    const int g = threadIdx.x;
    float p[64];
#pragma unroll
    for (int i = 0; i < 64; ++i) p[i] = pooled[g * 64 + i];
    float o = b2[0];
#pragma unroll
    for (int j = 0; j < 16; ++j) {
        float hsum = b1[j];
#pragma unroll
        for (int i = 0; i < 64; ++i) hsum = fmaf(p[i], w1[i * 16 + j], hsum);
        o = fmaf(fmaxf(hsum, 0.f), w2[j], o);
    }
    out[g] = o;
}

// ------------------------------------------------------------------ launch
extern "C" void kernel_launch(void* const* d_in, const int* in_sizes, int n_in,
                              void* d_out, int out_size, void* d_ws,
                              size_t ws_size, hipStream_t stream) {
    const float* x     = (const float*)d_in[0];
    const float* ea    = (const float*)d_in[1];
    const int*   ei    = (const int*)d_in[2];
    const int*   batch = (const int*)d_in[3];
    const float* we1 = (const float*)d_in[4];
    const float* be1 = (const float*)d_in[5];
    const float* w1a = (const float*)d_in[6];
    const float* b1a = (const float*)d_in[7];
    const float* w1b = (const float*)d_in[8];
    const float* b1b = (const float*)d_in[9];
    const float* bn1g = (const float*)d_in[10];
    const float* bn1b = (const float*)d_in[11];
    const float* bn1m = (const float*)d_in[12];
    const float* bn1v = (const float*)d_in[13];
    const float* we2 = (const float*)d_in[14];
    const float* be2 = (const float*)d_in[15];
    const float* w2a = (const float*)d_in[16];
    const float* b2a = (const float*)d_in[17];
    const float* w2b = (const float*)d_in[18];
    const float* b2b = (const float*)d_in[19];
    const float* bn2g = (const float*)d_in[20];
    const float* bn2b = (const float*)d_in[21];
    const float* bn2m = (const float*)d_in[22];
    const float* bn2v = (const float*)d_in[23];
    const float* we3 = (const float*)d_in[24];
    const float* be3 = (const float*)d_in[25];
    const float* w3a = (const float*)d_in[26];
    const float* b3a = (const float*)d_in[27];
    const float* w3b = (const float*)d_in[28];
    const float* b3b = (const float*)d_in[29];
    const float* bn3g = (const float*)d_in[30];
    const float* bn3b = (const float*)d_in[31];
    const float* bn3m = (const float*)d_in[32];
    const float* bn3v = (const float*)d_in[33];
    const float* fc1w = (const float*)d_in[34];
    const float* fc1b = (const float*)d_in[35];
    const float* fc2w = (const float*)d_in[36];
    const float* fc2b = (const float*)d_in[37];

    const int N = in_sizes[0] / 64;
    const int E = in_sizes[1] / 16;
    const int M_pad = ((N + 255) / 256) * 256;
    const int* src = ei;
    const int* dst = ei + E;

    char* wsp = (char*)d_ws;
    auto alloc = [&](size_t bytes) -> void* {
        void* p = (void*)wsp;
        wsp += (bytes + 255) & ~(size_t)255;
        return p;
    };
    const int nb = (N + 255) / 256;
    int* deg    = (int*)alloc((size_t)N * 4);
    int* off    = (int*)alloc((size_t)(N + 1) * 4);
    int* cur    = (int*)alloc((size_t)N * 4);
    int* bsum   = (int*)alloc((size_t)nb * 4);
    int* srcs   = (int*)alloc((size_t)E * 4);
    uint_t* each = (uint_t*)alloc((size_t)E * 8 * 4);
    bf16* xb    = (bf16*)alloc((size_t)M_pad * 64 * 2);
    bf16* tb    = (bf16*)alloc((size_t)M_pad * 256 * 2);
    bf16* ub    = (bf16*)alloc((size_t)M_pad * 256 * 2);
    bf16* hb    = (bf16*)alloc((size_t)M_pad * 256 * 2);
    bf16* wt    = (bf16*)alloc((size_t)143360 * 2);
    uint_t* wef = (uint_t*)alloc((size_t)3584 * 4);
    float* pooled = (float*)alloc(128 * 64 * 4);

    bf16* wt1a = wt + 0;
    bf16* wt1b = wt + 16384;
    bf16* wt2a = wt + 81920;
    bf16* wt2b = wt + 114688;
    bf16* wt3a = wt + 131072;
    bf16* wt3b = wt + 139264;
    uint_t* wef1 = wef + 0;
    uint_t* wef2 = wef + 512;
    uint_t* wef3 = wef + 2560;

    // mega convert + zero (replaces 3 convs + 2 memsets)
    {
        int nx4 = N * 64 / 4;
        int total = nx4 + 143360 + 3584 + (N + 3) / 4 + 2048;
        megaconv_kernel<<<(total + 255) / 256, 256, 0, stream>>>(
            x, xb, nx4, w1a, w1b, w2a, w2b, w3a, w3b, wt, we1, we2, we3, wef,
            deg, N, pooled);
    }

    int eb = (E + 255) / 256;
    count_kernel<<<eb, 256, 0, stream>>>(dst, deg, E, N);
    scan1_kernel<<<nb, 256, 0, stream>>>(deg, bsum, N);
    scan3_kernel<<<nb, 256, 0, stream>>>(deg, bsum, off, cur, N, nb);
    fill_kernel<<<eb, 256, 0, stream>>>(src, dst, ea, cur, srcs, each, E, N);

    const int g256 = M_pad / 256;
    const int mblk = (N + 3) / 4;

    // ---- layer 1 (64 -> 256 -> 256)
    msg_fused<1><<<mblk, 256, 0, stream>>>(each, srcs, off, xb, wef1, be1, tb, N);
    gemm64<256><<<dim3(g256, 4), 256, 0, stream>>>(tb, wt1a, b1a, nullptr, nullptr,
                                                   nullptr, nullptr, ub, nullptr,
                                                   nullptr, N, 64, 1);
    gemm64<256><<<dim3(g256, 4), 256, 0, stream>>>(ub, wt1b, b1b, bn1g, bn1b, bn1m,
                                                   bn1v, hb, nullptr, nullptr,
                                                   N, 256, 2);
    // ---- layer 2 (256 -> 128 -> 128)
    msg_fused<4><<<mblk, 256, 0, stream>>>(each, srcs, off, hb, wef2, be2, tb, N);
    gemm64<128><<<dim3(g256, 2), 256, 0, stream>>>(tb, wt2a, b2a, nullptr, nullptr,
                                                   nullptr, nullptr, ub, nullptr,
                                                   nullptr, N, 256, 1);
    gemm64<128><<<dim3(g256, 2), 256, 0, stream>>>(ub, wt2b, b2b, bn2g, bn2b, bn2m,
                                                   bn2v, hb, nullptr, nullptr,
                                                   N, 128, 2);
    // ---- layer 3 (128 -> 64 -> 64) + fused pooling
    msg_fused<2><<<mblk, 256, 0, stream>>>(each, srcs, off, hb, wef3, be3, tb, N);
    gemm64<64><<<dim3(g256, 1), 256, 0, stream>>>(tb, wt3a, b3a, nullptr, nullptr,
                                                  nullptr, nullptr, ub, nullptr,
                                                  nullptr, N, 128, 1);
    gemm64<64><<<dim3(g256, 1), 256, 0, stream>>>(ub, wt3b, b3b, bn3g, bn3b, bn3m,
                                                  bn3v, nullptr, batch, pooled,
                                                  N, 64, 3);

    // ---- head
    head_kernel<<<1, 128, 0, stream>>>(pooled, fc1w, fc1b, fc2w, fc2b, (float*)d_out);
}

// Round 16
// 403.107 us; speedup vs baseline: 1.0418x; 1.0418x over previous
//
#include <hip/hip_runtime.h>
#include <hip/hip_bf16.h>

#define BN_EPS 1e-5f

typedef __attribute__((ext_vector_type(8))) short short8v;
typedef __attribute__((ext_vector_type(4))) float f32x4;
typedef _Float16 f16x2 __attribute__((ext_vector_type(2)));
typedef __hip_bfloat16 bf16;
typedef unsigned short ushort_t;
typedef unsigned int uint_t;

// ---------------------------------------------------------------- CSR build
__global__ void count_kernel(const int* __restrict__ dst, int* __restrict__ deg,
                             int E, int N) {
    int i = blockIdx.x * blockDim.x + threadIdx.x;
    if (i >= E) return;
    int d = dst[i];
    d = min(max(d, 0), N - 1);
    atomicAdd(&deg[d], 1);
}

// pass 1 — per-block sums (256 elems/block)
__global__ __launch_bounds__(256) void scan1_kernel(const int* __restrict__ deg,
                                                    int* __restrict__ bsum, int N) {
    int t = threadIdx.x, b = blockIdx.x;
    int i = b * 256 + t;
    int v = (i < N) ? deg[i] : 0;
#pragma unroll
    for (int d = 32; d; d >>= 1) v += __shfl_xor(v, d, 64);
    __shared__ int ws[4];
    if ((t & 63) == 0) ws[t >> 6] = v;
    __syncthreads();
    if (t == 0) bsum[b] = ws[0] + ws[1] + ws[2] + ws[3];
}

// pass 2 — per-block scan; block base computed internally from bsum[0..b)
__global__ __launch_bounds__(256) void scan3_kernel(const int* __restrict__ deg,
                                                    const int* __restrict__ bsum,
                                                    int* __restrict__ off,
                                                    int* __restrict__ cur,
                                                    int N, int nb) {
    int t = threadIdx.x, b = blockIdx.x;
    int lane = t & 63, w = t >> 6;

    int partial = 0;
    for (int j = t; j < b; j += 256) partial += bsum[j];
#pragma unroll
    for (int d = 32; d; d >>= 1) partial += __shfl_xor(partial, d, 64);
    __shared__ int bsm[4];
    if (lane == 0) bsm[w] = partial;
    __syncthreads();
    int base = bsm[0] + bsm[1] + bsm[2] + bsm[3];

    int i = b * 256 + t;
    int v = (i < N) ? deg[i] : 0;
    int inc = v;
#pragma unroll
    for (int d = 1; d < 64; d <<= 1) {
        int u = __shfl_up(inc, d, 64);
        if (lane >= d) inc += u;
    }
    __shared__ int ws[4];
    if (lane == 63) ws[w] = inc;
    __syncthreads();
    for (int j = 0; j < w; ++j) base += ws[j];
    int excl = base + inc - v;
    if (i < N) { off[i] = excl; cur[i] = excl; }
    if (i == N - 1) off[N] = excl + v;
}

// fill: CSR edge placement; emits permuted src ids AND permuted edge_attr
// packed as 8 x (2 x f16) per edge
__global__ void fill_kernel(const int* __restrict__ src, const int* __restrict__ dst,
                            const float* __restrict__ ea, int* __restrict__ cur,
                            int* __restrict__ srcs, uint_t* __restrict__ each,
                            int E, int N) {
    int i = blockIdx.x * blockDim.x + threadIdx.x;
    if (i >= E) return;
    int d = dst[i];
    d = min(max(d, 0), N - 1);
    int p = atomicAdd(&cur[d], 1);
    srcs[p] = min(max(src[i], 0), N - 1);
    uint_t pk[8];
#pragma unroll
    for (int q = 0; q < 4; ++q) {
        float4 a = *(const float4*)&ea[(size_t)i * 16 + q * 4];
        f16x2 h0 = {(_Float16)a.x, (_Float16)a.y};
        f16x2 h1 = {(_Float16)a.z, (_Float16)a.w};
        pk[q * 2 + 0] = __builtin_bit_cast(uint_t, h0);
        pk[q * 2 + 1] = __builtin_bit_cast(uint_t, h1);
    }
    *(uint4*)&each[(size_t)p * 8 + 0] = *(uint4*)&pk[0];
    *(uint4*)&each[(size_t)p * 8 + 4] = *(uint4*)&pk[4];
}

// ------------------------------------------- mega convert + zero kernel
// MLP weights packed into MFMA B-fragment order:
//   wt[base + ((nt*ktn + kt)*64 + lane)*8 + j] = w[k][col]
//   col = nt*16 + (lane&15),  k = kt*32 + (lane>>4)*8 + j
// -> a wave's fragment load is lane-contiguous (1 KB coalesced).
__global__ void megaconv_kernel(
    const float* __restrict__ x, bf16* __restrict__ xb, int nx4,
    const float* __restrict__ w1a, const float* __restrict__ w1b,
    const float* __restrict__ w2a, const float* __restrict__ w2b,
    const float* __restrict__ w3a, const float* __restrict__ w3b,
    bf16* __restrict__ wt,
    const float* __restrict__ we1, const float* __restrict__ we2,
    const float* __restrict__ we3, uint_t* __restrict__ wef,
    int* __restrict__ deg, int N, float* __restrict__ pooled) {
    int t = blockIdx.x * blockDim.x + threadIdx.x;
    if (t < nx4) {
        int i = t * 4;
        float4 v = *(const float4*)&x[i];
        xb[i + 0] = __float2bfloat16(v.x);
        xb[i + 1] = __float2bfloat16(v.y);
        xb[i + 2] = __float2bfloat16(v.z);
        xb[i + 3] = __float2bfloat16(v.w);
        return;
    }
    t -= nx4;
    if (t < 143360) {
        const float* w; int K, Nc, base, r;
        if (t < 16384)       { w = w1a; K = 64;  Nc = 256; base = 0;      r = t; }
        else if (t < 81920)  { w = w1b; K = 256; Nc = 256; base = 16384;  r = t - 16384; }
        else if (t < 114688) { w = w2a; K = 256; Nc = 128; base = 81920;  r = t - 81920; }
        else if (t < 131072) { w = w2b; K = 128; Nc = 128; base = 114688; r = t - 114688; }
        else if (t < 139264) { w = w3a; K = 128; Nc = 64;  base = 131072; r = t - 131072; }
        else                 { w = w3b; K = 64;  Nc = 64;  base = 139264; r = t - 139264; }
        int ktn = K / 32;
        int j = r & 7;
        int lane = (r >> 3) & 63;
        int rem = r >> 9;
        int kt = rem % ktn;
        int nt = rem / ktn;
        int col = nt * 16 + (lane & 15);
        int k = kt * 32 + ((lane >> 4) << 3) + j;
        wt[base + r] = __float2bfloat16(w[(size_t)k * Nc + col]);
        return;
    }
    t -= 143360;
    if (t < 3584) {
        const float* w; int D, base, r;
        if (t < 512)        { w = we1; D = 64;  base = 0;    r = t; }
        else if (t < 2560)  { w = we2; D = 256; base = 512;  r = t - 512; }
        else                { w = we3; D = 128; base = 2560; r = t - 2560; }
        int p = r / D, col = r % D;
        f16x2 h = {(_Float16)w[(size_t)(2 * p) * D + col],
                   (_Float16)w[(size_t)(2 * p + 1) * D + col]};
        wef[base + r] = __builtin_bit_cast(uint_t, h);
        return;
    }
    t -= 3584;
    {
        int nd4 = (N + 3) / 4;
        if (t < nd4) {
            int i = t * 4;
#pragma unroll
            for (int j = 0; j < 4; ++j)
                if (i + j < N) deg[i + j] = 0;
            return;
        }
        t -= nd4;
        if (t < 2048) {
            *(float4*)&pooled[t * 4] = make_float4(0.f, 0.f, 0.f, 0.f);
        }
    }
}

// ------------------------------------------------- fused message + aggregate
// (r14 body — best known; jointly gather-BW + VALU bound, 6 attempts pinned)
template <int C>
__global__ __launch_bounds__(256) void msg_fused(
    const uint_t* __restrict__ each, const int* __restrict__ srcs,
    const int* __restrict__ off, const bf16* __restrict__ x,
    const uint_t* __restrict__ wef, const float* __restrict__ be,
    bf16* __restrict__ t, int N) {
    constexpr int D = C * 64;
    const int lane = threadIdx.x & 63;
    const int n = blockIdx.x * 4 + (threadIdx.x >> 6);
    if (n >= N) return;
    const int col0 = lane * C;

    uint_t wreg[8][C];
#pragma unroll
    for (int p = 0; p < 8; ++p)
#pragma unroll
        for (int c = 0; c < C; ++c) wreg[p][c] = wef[p * D + col0 + c];
    float breg[C];
#pragma unroll
    for (int c = 0; c < C; ++c) breg[c] = be[col0 + c];

    float acc[C];
#pragma unroll
    for (int c = 0; c < C; ++c) acc[c] = 0.f;

    const ushort_t* xp = (const ushort_t*)x;

    const int i0 = __builtin_amdgcn_readfirstlane(off[n]);
    const int i1 = __builtin_amdgcn_readfirstlane(off[n + 1]);

#define BF2F(u) (__builtin_bit_cast(float, (unsigned)(u) << 16))
#define H2(u) (__builtin_bit_cast(f16x2, u))

    int i = i0;
    int sN[4] = {0, 0, 0, 0};
    if (i + 4 <= i1) {
#pragma unroll
        for (int j = 0; j < 4; ++j)
            sN[j] = __builtin_amdgcn_readfirstlane(srcs[i + j]);
    }
    for (; i + 4 <= i1; i += 4) {
        int s[4];
#pragma unroll
        for (int j = 0; j < 4; ++j) s[j] = sN[j];
        ushort_t xv[4][C];
#pragma unroll
        for (int j = 0; j < 4; ++j) {
            if constexpr (C == 4) {
                *(ushort4*)xv[j] = *(const ushort4*)&xp[(size_t)s[j] * D + col0];
            } else if constexpr (C == 2) {
                *(ushort2*)xv[j] = *(const ushort2*)&xp[(size_t)s[j] * D + col0];
            } else {
                xv[j][0] = xp[(size_t)s[j] * D + col0];
            }
        }
        if (i + 8 <= i1) {
#pragma unroll
            for (int j = 0; j < 4; ++j)
                sN[j] = __builtin_amdgcn_readfirstlane(srcs[i + 4 + j]);
        }
        uint_t e[4][8];
#pragma unroll
        for (int j = 0; j < 4; ++j)
#pragma unroll
            for (int p = 0; p < 8; ++p) e[j][p] = each[(size_t)(i + j) * 8 + p];

        float m[4][C];
#pragma unroll
        for (int j = 0; j < 4; ++j)
#pragma unroll
            for (int c = 0; c < C; ++c)
                m[j][c] = __builtin_amdgcn_fdot2(H2(e[j][0]), H2(wreg[0][c]), breg[c], false);
#pragma unroll
        for (int p = 1; p < 8; ++p)
#pragma unroll
            for (int j = 0; j < 4; ++j)
#pragma unroll
                for (int c = 0; c < C; ++c)
                    m[j][c] = __builtin_amdgcn_fdot2(H2(e[j][p]), H2(wreg[p][c]), m[j][c], false);
#pragma unroll
        for (int j = 0; j < 4; ++j)
#pragma unroll
            for (int c = 0; c < C; ++c)
                acc[c] += fmaxf(m[j][c] + BF2F(xv[j][c]), 0.f);
    }
    for (; i < i1; ++i) {
        const int s0 = __builtin_amdgcn_readfirstlane(srcs[i]);
        ushort_t xv0[C];
        if constexpr (C == 4) {
            *(ushort4*)xv0 = *(const ushort4*)&xp[(size_t)s0 * D + col0];
        } else if constexpr (C == 2) {
            *(ushort2*)xv0 = *(const ushort2*)&xp[(size_t)s0 * D + col0];
        } else {
            xv0[0] = xp[(size_t)s0 * D + col0];
        }
        uint_t e0[8];
#pragma unroll
        for (int p = 0; p < 8; ++p) e0[p] = each[(size_t)i * 8 + p];
        float m0[C];
#pragma unroll
        for (int c = 0; c < C; ++c)
            m0[c] = __builtin_amdgcn_fdot2(H2(e0[0]), H2(wreg[0][c]), breg[c], false);
#pragma unroll
        for (int p = 1; p < 8; ++p)
#pragma unroll
            for (int c = 0; c < C; ++c)
                m0[c] = __builtin_amdgcn_fdot2(H2(e0[p]), H2(wreg[p][c]), m0[c], false);
#pragma unroll
        for (int c = 0; c < C; ++c) acc[c] += fmaxf(m0[c] + BF2F(xv0[c]), 0.f);
    }

#pragma unroll
    for (int c = 0; c < C; ++c) {
        float xo = BF2F(xp[(size_t)n * D + col0 + c]);
        t[(size_t)n * D + col0 + c] = __float2bfloat16(xo + acc[c]);
    }
#undef BF2F
#undef H2
}

// --------------------------------------------------------- fused 2-GEMM MLP
// out = epi( relu(A @ W1 + b1) @ W2 + b2 );  W1/W2 pre-packed in MFMA
// fragment order (1 KB lane-contiguous B loads — fixes r9's 16-segment
// scatter). 16 rows/wave, u slice wave-private in LDS (no barrier).
// A read ONCE (no per-y-tile re-read), no ub round-trip.
// mode 2: bn(relu) -> C    mode 3: bn(relu) + atomic pool (no C write)
template <int H, int NC>
__global__ __launch_bounds__(256) void mlp_fused(
    const bf16* __restrict__ A, const bf16* __restrict__ W1p_,
    const float* __restrict__ b1, const bf16* __restrict__ W2p_,
    const float* __restrict__ b2, const float* __restrict__ bng,
    const float* __restrict__ bnb, const float* __restrict__ bnm,
    const float* __restrict__ bnv, bf16* __restrict__ C,
    const int* __restrict__ batch, float* __restrict__ pooled,
    int M, int K1, int mode) {
    constexpr int NT1 = H / 16;
    constexpr int NT2 = NC / 16;
    constexpr int LDH = H + 8;   // pad: rows land on shifted banks
    __shared__ __align__(16) ushort_t u_lds[4 * 16 * LDH];

    const int lane = threadIdx.x & 63;
    const int w = threadIdx.x >> 6;
    const int r16 = lane & 15;
    const int kg = lane >> 4;
    const int mbase = blockIdx.x * 64 + w * 16;
    ushort_t* uw = &u_lds[w * 16 * LDH];

    const short* Ap = (const short*)A;
    const short* W1p = (const short*)W1p_;
    const short* W2p = (const short*)W2p_;
    const int ktn1 = K1 >> 5;

    // ---- stage 1: u = relu(A @ W1 + b1) -> wave-private LDS (bf16)
    {
        f32x4 acc1[NT1];
#pragma unroll
        for (int nt = 0; nt < NT1; ++nt) acc1[nt] = (f32x4){0.f, 0.f, 0.f, 0.f};

        for (int kt = 0; kt < ktn1; ++kt) {
            short8v a = *(const short8v*)&Ap[(size_t)(mbase + r16) * K1 + kt * 32 + kg * 8];
#pragma unroll
            for (int nt = 0; nt < NT1; ++nt) {
                short8v b = *(const short8v*)&W1p[(((size_t)nt * ktn1 + kt) * 64 + lane) * 8];
                acc1[nt] = __builtin_amdgcn_mfma_f32_16x16x32_bf16(a, b, acc1[nt], 0, 0, 0);
            }
        }
#pragma unroll
        for (int nt = 0; nt < NT1; ++nt) {
            int col = nt * 16 + r16;
            float bs = b1[col];
#pragma unroll
            for (int rg = 0; rg < 4; ++rg) {
                float z = fmaxf(acc1[nt][rg] + bs, 0.f);
                uw[(kg * 4 + rg) * LDH + col] =
                    __builtin_bit_cast(ushort_t, __float2bfloat16(z));
            }
        }
    }
    // no __syncthreads: wave reads only its own slice (lgkmcnt orders it)

    // ---- stage 2: out = epi(u @ W2 + b2)
    constexpr int ktn2 = H >> 5;
    f32x4 acc2[NT2];
#pragma unroll
    for (int nt = 0; nt < NT2; ++nt) acc2[nt] = (f32x4){0.f, 0.f, 0.f, 0.f};

    for (int kt = 0; kt < ktn2; ++kt) {
        short8v a = *(const short8v*)&uw[r16 * LDH + kt * 32 + kg * 8];
#pragma unroll
        for (int nt = 0; nt < NT2; ++nt) {
            short8v b = *(const short8v*)&W2p[(((size_t)nt * ktn2 + kt) * 64 + lane) * 8];
            acc2[nt] = __builtin_amdgcn_mfma_f32_16x16x32_bf16(a, b, acc2[nt], 0, 0, 0);
        }
    }

    float bs[NT2], sc[NT2], sh[NT2];
#pragma unroll
    for (int nt = 0; nt < NT2; ++nt) {
        int col = nt * 16 + r16;
        bs[nt] = b2[col];
        sc[nt] = rsqrtf(bnv[col] + BN_EPS) * bng[col];
        sh[nt] = bnb[col] - bnm[col] * sc[nt];
    }

#pragma unroll
    for (int rg = 0; rg < 4; ++rg) {
        int row = mbase + kg * 4 + rg;
        if (row >= M) continue;
        int g = 0;
        if (mode == 3) g = min(max(batch[row], 0), 127);
#pragma unroll
        for (int nt = 0; nt < NT2; ++nt) {
            int col = nt * 16 + r16;
            float z = fmaxf(acc2[nt][rg] + bs[nt], 0.f);
            z = z * sc[nt] + sh[nt];
            if (mode == 3)
                atomicAdd(&pooled[g * NC + col], z);
            else
                C[(size_t)row * NC + col] = __float2bfloat16(z);
        }
    }
}

// -------------------------------------------------------------------- head
__global__ __launch_bounds__(128) void head_kernel(
    const float* __restrict__ pooled, const float* __restrict__ w1,
    const float* __restrict__ b1, const float* __restrict__ w2,
    const float* __restrict__ b2, float* __restrict__ out) {
    const int g = threadIdx.x;
    float p[64];
#pragma unroll
    for (int i = 0; i < 64; ++i) p[i] = pooled[g * 64 + i];
    float o = b2[0];
#pragma unroll
    for (int j = 0; j < 16; ++j) {
        float hsum = b1[j];
#pragma unroll
        for (int i = 0; i < 64; ++i) hsum = fmaf(p[i], w1[i * 16 + j], hsum);
        o = fmaf(fmaxf(hsum, 0.f), w2[j], o);
    }
    out[g] = o;
}

// ------------------------------------------------------------------ launch
extern "C" void kernel_launch(void* const* d_in, const int* in_sizes, int n_in,
                              void* d_out, int out_size, void* d_ws,
                              size_t ws_size, hipStream_t stream) {
    const float* x     = (const float*)d_in[0];
    const float* ea    = (const float*)d_in[1];
    const int*   ei    = (const int*)d_in[2];
    const int*   batch = (const int*)d_in[3];
    const float* we1 = (const float*)d_in[4];
    const float* be1 = (const float*)d_in[5];
    const float* w1a = (const float*)d_in[6];
    const float* b1a = (const float*)d_in[7];
    const float* w1b = (const float*)d_in[8];
    const float* b1b = (const float*)d_in[9];
    const float* bn1g = (const float*)d_in[10];
    const float* bn1b = (const float*)d_in[11];
    const float* bn1m = (const float*)d_in[12];
    const float* bn1v = (const float*)d_in[13];
    const float* we2 = (const float*)d_in[14];
    const float* be2 = (const float*)d_in[15];
    const float* w2a = (const float*)d_in[16];
    const float* b2a = (const float*)d_in[17];
    const float* w2b = (const float*)d_in[18];
    const float* b2b = (const float*)d_in[19];
    const float* bn2g = (const float*)d_in[20];
    const float* bn2b = (const float*)d_in[21];
    const float* bn2m = (const float*)d_in[22];
    const float* bn2v = (const float*)d_in[23];
    const float* we3 = (const float*)d_in[24];
    const float* be3 = (const float*)d_in[25];
    const float* w3a = (const float*)d_in[26];
    const float* b3a = (const float*)d_in[27];
    const float* w3b = (const float*)d_in[28];
    const float* b3b = (const float*)d_in[29];
    const float* bn3g = (const float*)d_in[30];
    const float* bn3b = (const float*)d_in[31];
    const float* bn3m = (const float*)d_in[32];
    const float* bn3v = (const float*)d_in[33];
    const float* fc1w = (const float*)d_in[34];
    const float* fc1b = (const float*)d_in[35];
    const float* fc2w = (const float*)d_in[36];
    const float* fc2b = (const float*)d_in[37];

    const int N = in_sizes[0] / 64;
    const int E = in_sizes[1] / 16;
    const int M_pad = ((N + 63) / 64) * 64;
    const int* src = ei;
    const int* dst = ei + E;

    char* wsp = (char*)d_ws;
    auto alloc = [&](size_t bytes) -> void* {
        void* p = (void*)wsp;
        wsp += (bytes + 255) & ~(size_t)255;
        return p;
    };
    const int nb = (N + 255) / 256;
    int* deg    = (int*)alloc((size_t)N * 4);
    int* off    = (int*)alloc((size_t)(N + 1) * 4);
    int* cur    = (int*)alloc((size_t)N * 4);
    int* bsum   = (int*)alloc((size_t)nb * 4);
    int* srcs   = (int*)alloc((size_t)E * 4);
    uint_t* each = (uint_t*)alloc((size_t)E * 8 * 4);
    bf16* xb    = (bf16*)alloc((size_t)M_pad * 64 * 2);
    bf16* tb    = (bf16*)alloc((size_t)M_pad * 256 * 2);
    bf16* hb    = (bf16*)alloc((size_t)M_pad * 256 * 2);
    bf16* wt    = (bf16*)alloc((size_t)143360 * 2);
    uint_t* wef = (uint_t*)alloc((size_t)3584 * 4);
    float* pooled = (float*)alloc(128 * 64 * 4);

    bf16* wt1a = wt + 0;
    bf16* wt1b = wt + 16384;
    bf16* wt2a = wt + 81920;
    bf16* wt2b = wt + 114688;
    bf16* wt3a = wt + 131072;
    bf16* wt3b = wt + 139264;
    uint_t* wef1 = wef + 0;
    uint_t* wef2 = wef + 512;
    uint_t* wef3 = wef + 2560;

    // mega convert + zero (replaces 3 convs + 2 memsets)
    {
        int nx4 = N * 64 / 4;
        int total = nx4 + 143360 + 3584 + (N + 3) / 4 + 2048;
        megaconv_kernel<<<(total + 255) / 256, 256, 0, stream>>>(
            x, xb, nx4, w1a, w1b, w2a, w2b, w3a, w3b, wt, we1, we2, we3, wef,
            deg, N, pooled);
    }

    int eb = (E + 255) / 256;
    count_kernel<<<eb, 256, 0, stream>>>(dst, deg, E, N);
    scan1_kernel<<<nb, 256, 0, stream>>>(deg, bsum, N);
    scan3_kernel<<<nb, 256, 0, stream>>>(deg, bsum, off, cur, N, nb);
    fill_kernel<<<eb, 256, 0, stream>>>(src, dst, ea, cur, srcs, each, E, N);

    const int g64 = M_pad / 64;
    const int mblk = (N + 3) / 4;

    // ---- layer 1 (64 -> 256 -> 256)
    msg_fused<1><<<mblk, 256, 0, stream>>>(each, srcs, off, xb, wef1, be1, tb, N);
    mlp_fused<256, 256><<<g64, 256, 0, stream>>>(tb, wt1a, b1a, wt1b, b1b,
                                                 bn1g, bn1b, bn1m, bn1v,
                                                 hb, nullptr, nullptr, N, 64, 2);
    // ---- layer 2 (256 -> 128 -> 128)
    msg_fused<4><<<mblk, 256, 0, stream>>>(each, srcs, off, hb, wef2, be2, tb, N);
    mlp_fused<128, 128><<<g64, 256, 0, stream>>>(tb, wt2a, b2a, wt2b, b2b,
                                                 bn2g, bn2b, bn2m, bn2v,
                                                 hb, nullptr, nullptr, N, 256, 2);
    // ---- layer 3 (128 -> 64 -> 64) + fused pooling
    msg_fused<2><<<mblk, 256, 0, stream>>>(each, srcs, off, hb, wef3, be3, tb, N);
    mlp_fused<64, 64><<<g64, 256, 0, stream>>>(tb, wt3a, b3a, wt3b, b3b,
                                               bn3g, bn3b, bn3m, bn3v,
                                               nullptr, batch, pooled, N, 128, 3);

    // ---- head
    head_kernel<<<1, 128, 0, stream>>>(pooled, fc1w, fc1b, fc2w, fc2b, (float*)d_out);
}